// Round 1
// baseline (541.086 us; speedup 1.0000x reference)
//
#include <hip/hip_runtime.h>
#include <math.h>

#define NPTS 32768
#define NIMG 32          // B*C = 8*4
#define GRID_N 256
#define IMG_N 128

// ---------- I0 Bessel, fully unrolled so 1/(m*m) constant-folds ----------
static __device__ __forceinline__ double bessel_i0d(double x) {
    double hx2 = 0.25 * x * x;
    double t = 1.0, s = 1.0;
#pragma unroll
    for (int m = 1; m <= 40; ++m) {
        t *= hx2 * (1.0 / ((double)m * (double)m));
        s += t;
    }
    return s;
}

// ---------- S[d] = sum_{x<128} ax[x] * exp(2*pi*i * x * d / 256) ----------
__global__ void k_setup_S(float2* __restrict__ S) {
    __shared__ float ax[128];
    int t = threadIdx.x;              // 0..255
    if (t < 128) {
        double i0a = bessel_i0d(14.04);
        double om = ((double)t - 63.5) * (1.0 / 256.0);
        double pj = M_PI * 6.0 * om;
        double tt = sqrt(14.04 * 14.04 - pj * pj);   // always real here
        double kbft = 6.0 * (sinh(tt) / tt) / i0a;
        ax[t] = (float)(1.0 / kbft);                 // apodization 1D
    }
    __syncthreads();
    double re = 0.0, im = 0.0;
    for (int x = 0; x < 128; ++x) {
        int ph = (x * t) & 255;                      // exact phase reduction
        double ang = (double)ph * (2.0 * M_PI / 256.0);
        re += (double)ax[x] * cos(ang);
        im += (double)ax[x] * sin(ang);
    }
    S[t] = make_float2((float)re, (float)im);
}

// ---------- per-point KB weights / wrapped indices ----------
__global__ void k_weights(const float* __restrict__ coords,
                          float* __restrict__ wx, float* __restrict__ wy,
                          int* __restrict__ kx, int* __restrict__ ky) {
    int k = blockIdx.x * blockDim.x + threadIdx.x;
    if (k >= NPTS) return;
    double i0a = bessel_i0d(14.04);
#pragma unroll
    for (int dim = 0; dim < 2; ++dim) {
        float cv = coords[2 * k + dim];
        float gm = cv * (float)(256.0 / (2.0 * M_PI));
        float base = floorf(gm - 3.0f);
        float* wptr = dim ? wy : wx;
        int* kptr = dim ? ky : kx;
#pragma unroll
        for (int j = 0; j < 6; ++j) {
            float kk = base + (float)(j + 1);
            float u = gm - kk;
            float r = (2.0f * u) / 6.0f;
            float arg = 1.0f - r * r;
            float w = 0.0f;
            if (arg > 0.0f) {
                double a = sqrt(fmax((double)arg, 1e-12));
                w = (float)(bessel_i0d(14.04 * a) / i0a);
            }
            wptr[k * 6 + j] = w;
            kptr[k * 6 + j] = (((int)kk) + 256) & 255;
        }
    }
}

// ---------- gridding: scatter-add real contributions ----------
__global__ void k_grid(const float* __restrict__ values,
                       const float* __restrict__ wx, const float* __restrict__ wy,
                       const int* __restrict__ kx, const int* __restrict__ ky,
                       float* __restrict__ grid) {
    int idx = blockIdx.x * blockDim.x + threadIdx.x;   // k*36 + tap
    if (idx >= NPTS * 36) return;
    int k = idx / 36;
    int tap = idx - k * 36;
    int jx = tap / 6, jy = tap - jx * 6;
    float w = wx[k * 6 + jx] * wy[k * 6 + jy];
    int cell = (kx[k * 6 + jx] << 8) | ky[k * 6 + jy];
#pragma unroll
    for (int img = 0; img < NIMG; ++img) {
        atomicAdd(&grid[img * 65536 + cell], values[img * NPTS + k] * w);
    }
}

// ---------- mm1: T1[img,p,v] = sum_u S[(u-2p)&255] * G[img,u,v] ----------
__global__ void k_mm1(const float* __restrict__ grid, const float2* __restrict__ S,
                      float2* __restrict__ T1) {
    __shared__ float2 ssh[256];
    int v = threadIdx.x;          // 0..255
    int img = blockIdx.x;         // 0..31
    int p0 = blockIdx.y * 4;      // 4 p-rows per block (reuse grid row loads)
    ssh[v] = S[v];
    __syncthreads();
    const float* g = grid + img * 65536;
    float re[4] = {0, 0, 0, 0}, im[4] = {0, 0, 0, 0};
    for (int u = 0; u < 256; ++u) {
        float gv = g[(u << 8) + v];
#pragma unroll
        for (int i = 0; i < 4; ++i) {
            float2 s = ssh[(u - 2 * (p0 + i)) & 255];
            re[i] += s.x * gv;
            im[i] += s.y * gv;
        }
    }
#pragma unroll
    for (int i = 0; i < 4; ++i)
        T1[((img * 128 + p0 + i) << 8) + v] = make_float2(re[i], im[i]);
}

// ---------- mm2: F[img,p,q] = sum_v T1[img,p,v] * S[(v-2q)&255]; |F| + fftshift ----------
__global__ void k_mm2(const float2* __restrict__ T1, const float2* __restrict__ S,
                      float* __restrict__ out) {
    __shared__ float sre[256], sim[256];
    __shared__ float2 trow[256];
    int q = threadIdx.x;          // 0..127
    int img = blockIdx.x;         // 0..31
    int p = blockIdx.y;           // 0..127
    float2 s0 = S[q];       sre[q] = s0.x;        sim[q] = s0.y;
    float2 s1 = S[q + 128]; sre[q + 128] = s1.x;  sim[q + 128] = s1.y;
    const float2* tr = T1 + (img * 128 + p) * 256;
    trow[q] = tr[q];
    trow[q + 128] = tr[q + 128];
    __syncthreads();
    float re = 0.f, im = 0.f;
    for (int v = 0; v < 256; ++v) {
        float2 t = trow[v];                  // wave-uniform -> LDS broadcast
        int si = (v - 2 * q) & 255;
        float srv = sre[si], siv = sim[si];
        re += t.x * srv - t.y * siv;
        im += t.x * siv + t.y * srv;
    }
    float mag = sqrtf(re * re + im * im);
    int b = img >> 2, c = img & 3;
    // fftshift over ALL dims: (i - n/2) mod n == i XOR n/2 for these sizes
    out[((((b ^ 4) * 4 + (c ^ 2)) * 128 + (p ^ 64)) << 7) + (q ^ 64)] = mag;
}

extern "C" void kernel_launch(void* const* d_in, const int* in_sizes, int n_in,
                              void* d_out, int out_size, void* d_ws, size_t ws_size,
                              hipStream_t stream) {
    const float* values = (const float*)d_in[0];   // [8,4,32768] f32
    const float* coords = (const float*)d_in[1];   // [32768,2] f32

    char* ws = (char*)d_ws;
    float2* S   = (float2*)(ws + 0);            // 2 KB
    float* wx   = (float*)(ws + 2048);          // 768 KB
    float* wy   = (float*)(ws + 788480);        // 768 KB
    int*   kx   = (int*)(ws + 1574912);         // 768 KB
    int*   ky   = (int*)(ws + 2361344);         // 768 KB
    float* grid = (float*)(ws + 3147776);       // 8 MB  (32 x 256 x 256 f32, real)
    float2* T1  = (float2*)(ws + 11536384);     // 8 MB  (32 x 128 x 256 c64)

    hipMemsetAsync(grid, 0, (size_t)NIMG * 65536 * sizeof(float), stream);

    k_setup_S<<<1, 256, 0, stream>>>(S);
    k_weights<<<(NPTS + 255) / 256, 256, 0, stream>>>(coords, wx, wy, kx, ky);
    k_grid<<<(NPTS * 36 + 255) / 256, 256, 0, stream>>>(values, wx, wy, kx, ky, grid);
    k_mm1<<<dim3(32, 32), 256, 0, stream>>>(grid, S, T1);
    k_mm2<<<dim3(32, 128), 128, 0, stream>>>(T1, S, (float*)d_out);
}

// Round 2
// 300.080 us; speedup vs baseline: 1.8031x; 1.8031x over previous
//
#include <hip/hip_runtime.h>
#include <math.h>

#define NPTS 32768
#define NIMG 32          // B*C = 8*4
#define NPAIR (NPTS * 36)

// ---------- I0 Bessel (double, for setup) ----------
static __device__ __forceinline__ double bessel_i0d(double x) {
    double hx2 = 0.25 * x * x;
    double t = 1.0, s = 1.0;
#pragma unroll
    for (int m = 1; m <= 40; ++m) {
        t *= hx2 * (1.0 / ((double)m * (double)m));
        s += t;
    }
    return s;
}

// ---------- I0 Bessel (float, for per-point weights) ----------
static __device__ __forceinline__ float bessel_i0f(float x) {
    float hx2 = 0.25f * x * x;
    float t = 1.0f, s = 1.0f;
#pragma unroll
    for (int m = 1; m <= 40; ++m) {
        t *= hx2 * (1.0f / ((float)m * (float)m));
        s += t;
    }
    return s;
}

// ---------- S[d] = sum_{x<128} ax[x] * exp(2*pi*i * x * d / 256) ----------
__global__ void k_setup_S(float2* __restrict__ S) {
    __shared__ float ax[128];
    int t = threadIdx.x;              // 0..255
    if (t < 128) {
        double i0a = bessel_i0d(14.04);
        double om = ((double)t - 63.5) * (1.0 / 256.0);
        double pj = M_PI * 6.0 * om;
        double tt = sqrt(14.04 * 14.04 - pj * pj);   // always real here
        double kbft = 6.0 * (sinh(tt) / tt) / i0a;
        ax[t] = (float)(1.0 / kbft);                 // apodization 1D
    }
    __syncthreads();
    double re = 0.0, im = 0.0;
    for (int x = 0; x < 128; ++x) {
        int ph = (x * t) & 255;                      // exact phase reduction
        double ang = (double)ph * (2.0 * M_PI / 256.0);
        re += (double)ax[x] * cos(ang);
        im += (double)ax[x] * sin(ang);
    }
    S[t] = make_float2((float)re, (float)im);
}

// ---------- count contributions per grid cell ----------
__global__ void k_count(const float* __restrict__ coords, unsigned* __restrict__ counts) {
    int k = blockIdx.x * blockDim.x + threadIdx.x;
    if (k >= NPTS) return;
    float gmx = coords[2 * k]     * (float)(256.0 / (2.0 * M_PI));
    float gmy = coords[2 * k + 1] * (float)(256.0 / (2.0 * M_PI));
    float bx = floorf(gmx - 3.0f), by = floorf(gmy - 3.0f);
    int kx[6], ky[6];
#pragma unroll
    for (int j = 0; j < 6; ++j) {
        kx[j] = (((int)bx + j + 1) + 256) & 255;
        ky[j] = (((int)by + j + 1) + 256) & 255;
    }
#pragma unroll
    for (int jx = 0; jx < 6; ++jx)
#pragma unroll
        for (int jy = 0; jy < 6; ++jy)
            atomicAdd(&counts[(kx[jx] << 8) | ky[jy]], 1u);
}

// ---------- exclusive prefix sum of 65536 counts (single block) ----------
__global__ void k_scan(const unsigned* __restrict__ counts, unsigned* __restrict__ offsets) {
    __shared__ unsigned part[1024];
    int t = threadIdx.x;              // 0..1023, each owns 64 cells
    unsigned s = 0;
    for (int i = 0; i < 64; ++i) s += counts[t * 64 + i];
    part[t] = s;
    __syncthreads();
    for (int off = 1; off < 1024; off <<= 1) {
        unsigned v = (t >= off) ? part[t - off] : 0u;
        __syncthreads();
        part[t] += v;
        __syncthreads();
    }
    unsigned run = (t > 0) ? part[t - 1] : 0u;   // exclusive base
    for (int i = 0; i < 64; ++i) {
        offsets[t * 64 + i] = run;
        run += counts[t * 64 + i];
    }
}

// ---------- fill per-cell bins with packed (k,w) pairs ----------
// offsets[] is consumed as a cursor: after this kernel offsets[cell] == bin end.
__global__ void k_fill(const float* __restrict__ coords,
                       unsigned* __restrict__ offsets, unsigned* __restrict__ pairs) {
    int k = blockIdx.x * blockDim.x + threadIdx.x;
    if (k >= NPTS) return;
    float gmx = coords[2 * k]     * (float)(256.0 / (2.0 * M_PI));
    float gmy = coords[2 * k + 1] * (float)(256.0 / (2.0 * M_PI));
    float bx = floorf(gmx - 3.0f), by = floorf(gmy - 3.0f);
    const float inv_i0a = 1.0f / bessel_i0f(14.04f);   // constant-folds
    float wx[6], wy[6];
    int kx[6], ky[6];
#pragma unroll
    for (int j = 0; j < 6; ++j) {
        float kkx = bx + (float)(j + 1);
        float ux = gmx - kkx;
        float rx = ux * (1.0f / 3.0f);
        float ax = 1.0f - rx * rx;
        wx[j] = (ax > 0.0f) ? bessel_i0f(14.04f * sqrtf(ax)) * inv_i0a : 0.0f;
        kx[j] = (((int)kkx) + 256) & 255;
        float kky = by + (float)(j + 1);
        float uy = gmy - kky;
        float ry = uy * (1.0f / 3.0f);
        float ay = 1.0f - ry * ry;
        wy[j] = (ay > 0.0f) ? bessel_i0f(14.04f * sqrtf(ay)) * inv_i0a : 0.0f;
        ky[j] = (((int)kky) + 256) & 255;
    }
#pragma unroll
    for (int jx = 0; jx < 6; ++jx)
#pragma unroll
        for (int jy = 0; jy < 6; ++jy) {
            float w = wx[jx] * wy[jy];                  // in [0,1]
            unsigned cell = (unsigned)((kx[jx] << 8) | ky[jy]);
            unsigned pos = atomicAdd(&offsets[cell], 1u);
            unsigned q = (unsigned)(w * 131071.0f + 0.5f);
            if (q > 131071u) q = 131071u;
            pairs[pos] = ((unsigned)k << 17) | q;       // k:15b | w:17b fixed-point
        }
}

// ---------- transpose values [img][k] -> vt [k][img] ----------
__global__ void k_transpose(const float* __restrict__ values, float* __restrict__ vt) {
    __shared__ float tile[32][257];
    int kbase = blockIdx.x * 256;
    int t = threadIdx.x;
    for (int img = 0; img < 32; ++img)
        tile[img][t] = values[img * NPTS + kbase + t];
    __syncthreads();
    int img = t & 31;
    int k0 = t >> 5;                   // 0..7
    for (int r = 0; r < 32; ++r) {
        int kl = k0 + r * 8;           // 0..255
        vt[(kbase + kl) * 32 + img] = tile[img][kl];
    }
}

// ---------- gather: grid[img][cell] = sum over bin of w * vt[k][img] ----------
__global__ void k_gather(const unsigned* __restrict__ pairs,
                         const unsigned* __restrict__ counts,
                         const unsigned* __restrict__ ends,
                         const float* __restrict__ vt,
                         float* __restrict__ grid) {
    int t = threadIdx.x;
    int img = t & 31;
    int cell = blockIdx.x * 8 + (t >> 5);
    unsigned end = ends[cell];
    unsigned n = counts[cell];
    float acc = 0.0f;
    for (unsigned i = end - n; i < end; ++i) {
        unsigned pr = pairs[i];                         // broadcast across 32 lanes
        float w = (float)(pr & 0x1FFFFu) * (1.0f / 131071.0f);
        acc += w * vt[(pr >> 17) * 32 + img];           // coalesced 128B line
    }
    grid[img * 65536 + cell] = acc;
}

// ---------- mm1: T1[img,p,v] = sum_u S[(u-2p)&255] * G[img,u,v] ----------
__global__ void k_mm1(const float* __restrict__ grid, const float2* __restrict__ S,
                      float2* __restrict__ T1) {
    __shared__ float2 ssh[256];
    int v = threadIdx.x;          // 0..255
    int img = blockIdx.x;         // 0..31
    int p0 = blockIdx.y * 4;      // 4 p-rows per block
    ssh[v] = S[v];
    __syncthreads();
    const float* g = grid + img * 65536;
    float re[4] = {0, 0, 0, 0}, im[4] = {0, 0, 0, 0};
    for (int u = 0; u < 256; ++u) {
        float gv = g[(u << 8) + v];
#pragma unroll
        for (int i = 0; i < 4; ++i) {
            float2 s = ssh[(u - 2 * (p0 + i)) & 255];
            re[i] += s.x * gv;
            im[i] += s.y * gv;
        }
    }
#pragma unroll
    for (int i = 0; i < 4; ++i)
        T1[((img * 128 + p0 + i) << 8) + v] = make_float2(re[i], im[i]);
}

// ---------- mm2: F[img,p,q] = sum_v T1[img,p,v] * S[(v-2q)&255]; |F| + fftshift ----------
__global__ void k_mm2(const float2* __restrict__ T1, const float2* __restrict__ S,
                      float* __restrict__ out) {
    __shared__ float sre[256], sim[256];
    __shared__ float2 trow[256];
    int q = threadIdx.x;          // 0..127
    int img = blockIdx.x;         // 0..31
    int p = blockIdx.y;           // 0..127
    float2 s0 = S[q];       sre[q] = s0.x;        sim[q] = s0.y;
    float2 s1 = S[q + 128]; sre[q + 128] = s1.x;  sim[q + 128] = s1.y;
    const float2* tr = T1 + (img * 128 + p) * 256;
    trow[q] = tr[q];
    trow[q + 128] = tr[q + 128];
    __syncthreads();
    float re = 0.f, im = 0.f;
    for (int v = 0; v < 256; ++v) {
        float2 t = trow[v];                  // wave-uniform -> LDS broadcast
        int si = (v - 2 * q) & 255;
        float srv = sre[si], siv = sim[si];
        re += t.x * srv - t.y * siv;
        im += t.x * siv + t.y * srv;
    }
    float mag = sqrtf(re * re + im * im);
    int b = img >> 2, c = img & 3;
    out[((((b ^ 4) * 4 + (c ^ 2)) * 128 + (p ^ 64)) << 7) + (q ^ 64)] = mag;
}

extern "C" void kernel_launch(void* const* d_in, const int* in_sizes, int n_in,
                              void* d_out, int out_size, void* d_ws, size_t ws_size,
                              hipStream_t stream) {
    const float* values = (const float*)d_in[0];   // [8,4,32768] f32
    const float* coords = (const float*)d_in[1];   // [32768,2] f32

    char* ws = (char*)d_ws;
    // layout (total 17.0 MB):
    float2*   S       = (float2*)(ws + 0);                 // 2 KB
    unsigned* counts  = (unsigned*)(ws + 4096);            // 256 KB
    unsigned* offsets = (unsigned*)(ws + 266240);          // 256 KB (becomes end-cursors)
    unsigned* pairs   = (unsigned*)(ws + 528384);          // 4.5 MB  [dead after gather]
    float*    vt      = (float*)(ws + 5246976);            // 4 MB    [dead after gather]
    float*    grid    = (float*)(ws + 9441280);            // 8 MB    [dead after mm1]
    float2*   T1      = (float2*)(ws + 528384);            // 8 MB    [overlaps pairs+vt]

    hipMemsetAsync(counts, 0, 65536 * sizeof(unsigned), stream);

    k_setup_S<<<1, 256, 0, stream>>>(S);
    k_count<<<(NPTS + 255) / 256, 256, 0, stream>>>(coords, counts);
    k_scan<<<1, 1024, 0, stream>>>(counts, offsets);
    k_fill<<<(NPTS + 255) / 256, 256, 0, stream>>>(coords, offsets, pairs);
    k_transpose<<<NPTS / 256, 256, 0, stream>>>(values, vt);
    k_gather<<<65536 / 8, 256, 0, stream>>>(pairs, counts, offsets, vt, grid);
    k_mm1<<<dim3(32, 32), 256, 0, stream>>>(grid, S, T1);
    k_mm2<<<dim3(32, 128), 128, 0, stream>>>(T1, S, (float*)d_out);
}